// Round 9
// baseline (668.529 us; speedup 1.0000x reference)
//
#include <hip/hip_runtime.h>
#include <math.h>

#define N_NODES 50000
#define N_EDGES 800000
#define HID     128
#define N_ACT   64
#define N_GRAPH 512
#define N6      (N_NODES * 6)

// bucketing
#define NWF   2048
#define LOGW  11
#define WF    25
#define CAP   40960
#define CB    16
#define DC    16

// mega-kernel shape
#define G     400                  // grid (25*16); LDS allows 3 blk/CU -> all resident
#define T     512
#define NGRP  25                   // 16 blocks per barrier group
#define GPB   16
#define EPBLK 2000                 // 800000 / 400

// node stage
#define NBLK    128
#define MAXSPAN 16
#define NTILE   ((N_NODES + NBLK - 1) / NBLK)   // 391

// ws layout (int/float slots)
#define F_BUCKET 0                          // WF*CAP ints
#define F_BAR    (F_BUCKET + WF * CAP)      // 512 ints (barrier state)
#define F_CURSOR (F_BAR + 512)              // 32 ints
#define F_GSUM   (F_CURSOR + 32)            // N_GRAPH*HID
#define F_CNT    (F_GSUM + N_GRAPH * HID)   // N_GRAPH
#define F_DINV   (F_CNT + N_GRAPH)          // N_NODES
#define F_XSPAD  (F_DINV + N_NODES)         // N_NODES*8
#define F_DEGP   (F_XSPAD + N_NODES * 8)    // DC*N_NODES
#define F_SPART  (F_DEGP + DC * N_NODES)    // CB*N6
#define F_TOTAL  (F_SPART + CB * N6)
#define NEED_BYTES ((size_t)F_TOTAL * 4)

#define ZFLOATS (N_GRAPH * HID + N_GRAPH)        // gsum|cnt = 66048 (div by 4)
#define MAGIC64 0x7F4A91B3C25D6E19LL
#define SPIN_CAP 20000000L

// bar layout (ints): [0..1]=magic64  [4]=rootCnt  [8]=rootGen
//                    [16+g*16]=grpCnt[g]  [16+g*16+8]=grpGen[g]

__device__ __forceinline__ int rmw0(int* p) {
    return __hip_atomic_fetch_add(p, 0, __ATOMIC_SEQ_CST, __HIP_MEMORY_SCOPE_AGENT);
}
__device__ __forceinline__ int rmwadd(int* p, int v) {
    return __hip_atomic_fetch_add(p, v, __ATOMIC_SEQ_CST, __HIP_MEMORY_SCOPE_AGENT);
}

// hierarchical grid barrier; ALL polling via atomic RMW (memory-side, coherent
// across XCDs — plain atomic loads can spin on a stale per-XCD L2 line, the
// round-8 ~70us/barrier pathology). Counter resets use commutative adds.
__device__ __forceinline__ void gridbar(int* bar, int grp, int rootT, int grpT) {
    __syncthreads();
    if (threadIdx.x == 0) {
        __threadfence();   // release this block's stage writes (L2 wb)
        int* grpCnt  = bar + 16 + grp * 16;
        int* grpGen  = bar + 16 + grp * 16 + 8;
        int* rootCnt = bar + 4;
        int* rootGen = bar + 8;
        int old = rmwadd(grpCnt, 1);
        if (old == GPB - 1) {
            rmwadd(grpCnt, -GPB);              // reset (commutes with next-epoch +1s)
            int old2 = rmwadd(rootCnt, 1);
            if (old2 == NGRP - 1) {
                rmwadd(rootCnt, -NGRP);
                rmwadd(rootGen, 1);            // release leaders
            } else {
                long c = 0;
                while (rmw0(rootGen) != rootT && ++c < SPIN_CAP)
                    __builtin_amdgcn_s_sleep(8);
            }
            rmwadd(grpGen, 1);                 // release my 15 members
        } else {
            long c = 0;
            while (rmw0(grpGen) != grpT && ++c < SPIN_CAP)
                __builtin_amdgcn_s_sleep(8);
        }
        __threadfence();   // acquire side: drop stale lines before next stage reads
    }
    __syncthreads();
}

__global__ __launch_bounds__(T, 4) void k_mega(
    const float* __restrict__ x, const int* __restrict__ ei,
    const int* __restrict__ batch,
    const float* __restrict__ w1, const float* __restrict__ b1,
    const float* __restrict__ wl, const float* __restrict__ bl,
    const float* __restrict__ w2, const float* __restrict__ b2,
    float* __restrict__ out, float* __restrict__ ws)
{
    __shared__ __align__(16) char smem[49152];
    const int b = blockIdx.x, t = threadIdx.x;
    const int grp = b >> 4;
    int*   bar    = (int*)ws + F_BAR;
    int*   bucket = (int*)ws + F_BUCKET;
    int*   cursor = (int*)ws + F_CURSOR;
    float* gsum   = ws + F_GSUM;
    float* cnt    = ws + F_CNT;
    float* dinv   = ws + F_DINV;
    float* xs_pad = ws + F_XSPAD;
    float* degp   = ws + F_DEGP;
    float* s_part = ws + F_SPART;

    // ---- prologue: magic-guarded init (post-poison) + gen-base snapshot ----
    int baseRoot = 0, baseGrp = 0;
    if (t == 0) {
        long long* flag = (long long*)bar;
        long long f = __hip_atomic_fetch_add(flag, 0, __ATOMIC_SEQ_CST, __HIP_MEMORY_SCOPE_AGENT);
        if (f != MAGIC64) {
            if (b == 0) {
                for (int j = 4; j < 512; ++j) bar[j] = 0;
                for (int j = 0; j < 32; ++j) cursor[j] = 0;
                __threadfence();
                __hip_atomic_exchange(flag, MAGIC64, __ATOMIC_SEQ_CST, __HIP_MEMORY_SCOPE_AGENT);
            } else {
                long c = 0;
                while (__hip_atomic_fetch_add(flag, 0, __ATOMIC_SEQ_CST, __HIP_MEMORY_SCOPE_AGENT) != MAGIC64
                       && ++c < SPIN_CAP) __builtin_amdgcn_s_sleep(32);
            }
        }
        baseRoot = rmw0(bar + 8);
        baseGrp  = rmw0(bar + 16 + grp * 16 + 8);
    }
    __syncthreads();

    // ---- S1: place edges into dst-window buckets; spare lanes zero gsum|cnt ----
    {
        int tid = b * T + t;
        if (tid < ZFLOATS / 4)
            ((float4*)(ws + F_GSUM))[tid] = make_float4(0, 0, 0, 0);

        int* lc = (int*)smem;
        int* lb = lc + 32;
        if (t < WF) lc[t] = 0;
        __syncthreads();
        int e0 = b * EPBLK;
        int pk[4], wli[4];
#pragma unroll
        for (int i = 0; i < 4; ++i) {
            int e = e0 + i * T + t;
            wli[i] = -1;
            if (e < e0 + EPBLK) {
                int src = ei[e], dst = ei[N_EDGES + e];
                int w = dst >> LOGW;
                int lp = atomicAdd(&lc[w], 1);
                pk[i] = ((dst - (w << LOGW)) << 16) | src;
                wli[i] = (w << 16) | lp;
            }
        }
        __syncthreads();
        if (t < WF) lb[t] = atomicAdd(&cursor[t], lc[t]);
        __syncthreads();
#pragma unroll
        for (int i = 0; i < 4; ++i) {
            if (wli[i] >= 0) {
                int w = wli[i] >> 16, lp = wli[i] & 0xffff;
                int pos = lb[w] + lp;
                if (pos < CAP) bucket[w * CAP + pos] = pk[i];
            }
        }
    }
    gridbar(bar, grp, baseRoot + 1, baseGrp + 1);

    // ---- S2: degree partials (tile (w,c) = (b>>4, b&15)) ----
    {
        float* hist = (float*)smem;            // 2048 floats
        int w = b >> 4, c = b & 15;
        for (int i = t; i < NWF; i += T) hist[i] = 0.0f;
        __syncthreads();
        int cw = min(cursor[w], CAP);
        const int* bp = bucket + w * CAP;
        const int stride = DC * T;             // 8192
        int e = c * T + t;
        for (; e + 3 * stride < cw; e += 4 * stride) {
            int p0 = bp[e], p1 = bp[e + stride], p2 = bp[e + 2 * stride], p3 = bp[e + 3 * stride];
            atomicAdd(&hist[((unsigned)p0) >> 16], 1.0f);
            atomicAdd(&hist[((unsigned)p1) >> 16], 1.0f);
            atomicAdd(&hist[((unsigned)p2) >> 16], 1.0f);
            atomicAdd(&hist[((unsigned)p3) >> 16], 1.0f);
        }
        for (; e < cw; e += stride) atomicAdd(&hist[((unsigned)bp[e]) >> 16], 1.0f);
        __syncthreads();
        int nb = w * NWF;
        int lim = min(NWF, N_NODES - nb);
        for (int i = t; i < lim; i += T) degp[c * N_NODES + nb + i] = hist[i];
    }
    gridbar(bar, grp, baseRoot + 2, baseGrp + 2);

    // ---- S3: reduce degree -> dinv, xs_pad ----
    {
        int n = (b * T + t) * 2;
        if (n < N_NODES) {
            float d0 = 1.0f, d1 = 1.0f;
#pragma unroll
            for (int c = 0; c < DC; ++c) {
                d0 += degp[c * N_NODES + n];
                d1 += degp[c * N_NODES + n + 1];
            }
            float dv0 = rsqrtf(d0), dv1 = rsqrtf(d1);
            dinv[n] = dv0; dinv[n + 1] = dv1;
            const float4* xp = (const float4*)(x + (size_t)n * 6);
            float4 xa = xp[0], xb = xp[1], xc = xp[2];
            float4* op = (float4*)(xs_pad + (size_t)n * 8);
            op[0] = make_float4(xa.x * dv0, xa.y * dv0, xa.z * dv0, xa.w * dv0);
            op[1] = make_float4(xb.x * dv0, xb.y * dv0, 0.0f, 0.0f);
            op[2] = make_float4(xb.z * dv1, xb.w * dv1, xc.x * dv1, xc.y * dv1);
            op[3] = make_float4(xc.z * dv1, xc.w * dv1, 0.0f, 0.0f);
        }
    }
    gridbar(bar, grp, baseRoot + 3, baseGrp + 3);

    // ---- S4: feature scatter (tile (w,c)), batched gathers ----
    {
        float* h = (float*)smem;               // NWF*6 floats = 48 KB
        int w = b >> 4, c = b & 15;
        float4* h4 = (float4*)h;
        for (int i = t; i < NWF * 6 / 4; i += T) h4[i] = make_float4(0, 0, 0, 0);
        __syncthreads();
        int cw = min(cursor[w], CAP);
        const int* bp = bucket + w * CAP;
        const int stride = CB * T;             // 8192
        int e = c * T + t;
        for (; e + 3 * stride < cw; e += 4 * stride) {
            int p0 = bp[e], p1 = bp[e + stride], p2 = bp[e + 2 * stride], p3 = bp[e + 3 * stride];
            const float4* q0 = (const float4*)(xs_pad + (size_t)(p0 & 0xffff) * 8);
            const float4* q1 = (const float4*)(xs_pad + (size_t)(p1 & 0xffff) * 8);
            const float4* q2 = (const float4*)(xs_pad + (size_t)(p2 & 0xffff) * 8);
            const float4* q3 = (const float4*)(xs_pad + (size_t)(p3 & 0xffff) * 8);
            float4 a0 = q0[0], b0 = q0[1];
            float4 a1 = q1[0], b1 = q1[1];
            float4 a2 = q2[0], b2 = q2[1];
            float4 a3 = q3[0], b3 = q3[1];
            float* hp;
            hp = &h[(((unsigned)p0) >> 16) * 6];
            atomicAdd(hp + 0, a0.x); atomicAdd(hp + 1, a0.y); atomicAdd(hp + 2, a0.z);
            atomicAdd(hp + 3, a0.w); atomicAdd(hp + 4, b0.x); atomicAdd(hp + 5, b0.y);
            hp = &h[(((unsigned)p1) >> 16) * 6];
            atomicAdd(hp + 0, a1.x); atomicAdd(hp + 1, a1.y); atomicAdd(hp + 2, a1.z);
            atomicAdd(hp + 3, a1.w); atomicAdd(hp + 4, b1.x); atomicAdd(hp + 5, b1.y);
            hp = &h[(((unsigned)p2) >> 16) * 6];
            atomicAdd(hp + 0, a2.x); atomicAdd(hp + 1, a2.y); atomicAdd(hp + 2, a2.z);
            atomicAdd(hp + 3, a2.w); atomicAdd(hp + 4, b2.x); atomicAdd(hp + 5, b2.y);
            hp = &h[(((unsigned)p3) >> 16) * 6];
            atomicAdd(hp + 0, a3.x); atomicAdd(hp + 1, a3.y); atomicAdd(hp + 2, a3.z);
            atomicAdd(hp + 3, a3.w); atomicAdd(hp + 4, b3.x); atomicAdd(hp + 5, b3.y);
        }
        for (; e < cw; e += stride) {
            int p = bp[e];
            const float4* q = (const float4*)(xs_pad + (size_t)(p & 0xffff) * 8);
            float4 a = q[0], bb = q[1];
            float* hp = &h[(((unsigned)p) >> 16) * 6];
            atomicAdd(hp + 0, a.x); atomicAdd(hp + 1, a.y); atomicAdd(hp + 2, a.z);
            atomicAdd(hp + 3, a.w); atomicAdd(hp + 4, bb.x); atomicAdd(hp + 5, bb.y);
        }
        __syncthreads();
        int gb = w * NWF * 6;
        int lim = min(NWF * 6, N6 - gb);
        float4* sp4 = (float4*)(s_part + (size_t)c * N6 + gb);
        for (int i = t; i < lim / 4; i += T) sp4[i] = h4[i];
    }
    gridbar(bar, grp, baseRoot + 4, baseGrp + 4);

    // ---- S5: node W1+ReLU + per-graph accumulate (tiles b<NTILE);
    //          idle block 399 resets the 32 cursors for the next call ----
    {
        if (b == 399 && t < 32)
            __hip_atomic_exchange(cursor + t, 0, __ATOMIC_SEQ_CST, __HIP_MEMORY_SCOPE_AGENT);
        if (b < NTILE) {
            float* sb   = (float*)smem;                    // NBLK*6
            float* dvb  = sb + NBLK * 6;
            int*   btb  = (int*)(dvb + NBLK);
            float* gacc = (float*)(btb + NBLK);            // 16*128
            float* gcnt = gacc + MAXSPAN * HID;
            int*   sbnd = (int*)(gcnt + MAXSPAN);

            int nb0 = b * NBLK;
            int nEnd = min(nb0 + NBLK, N_NODES);
            int nCnt = nEnd - nb0;
            int lim = nCnt * 6;

            {
                float4* sb4 = (float4*)sb;
                int nv = lim >> 2;
                int g4base = (nb0 * 6) >> 2;
                for (int i = t; i < nv; i += T) {
                    float4 v = make_float4(0, 0, 0, 0);
#pragma unroll
                    for (int c = 0; c < CB; ++c) {
                        float4 p = ((const float4*)(s_part + (size_t)c * N6))[g4base + i];
                        v.x += p.x; v.y += p.y; v.z += p.z; v.w += p.w;
                    }
                    sb4[i] = v;
                }
            }
            for (int i = t; i < nCnt; i += T) {
                dvb[i] = dinv[nb0 + i];
                btb[i] = batch[nb0 + i];
            }
            if (t == 0) {
                sbnd[0] = (nb0 > 0) ? batch[nb0 - 1] : -1;
                sbnd[1] = (nEnd < N_NODES) ? batch[nEnd] : -1;
            }
            for (int i = t; i < MAXSPAN * HID; i += T) gacc[i] = 0.0f;
            if (t < MAXSPAN) gcnt[t] = 0.0f;
            __syncthreads();

            for (int i = t; i < nCnt; i += T) {
                const float4* xp = (const float4*)(xs_pad + (size_t)(nb0 + i) * 8);
                float4 a = xp[0], bb = xp[1];
                float* sp = &sb[i * 6];
                sp[0] += a.x; sp[1] += a.y; sp[2] += a.z;
                sp[3] += a.w; sp[4] += bb.x; sp[5] += bb.y;
            }
            __syncthreads();

            int f = t & (HID - 1);
            int sub = t >> 7;                              // 0..3
            float w1r[6];
#pragma unroll
            for (int k = 0; k < 6; ++k) w1r[k] = w1[k * HID + f];
            float b1f = b1[f];

            int bfirst = btb[0];
            int blast = btb[nCnt - 1];
            int span = blast - bfirst + 1;
            int bprev = sbnd[0], bnext = sbnd[1];
            int i0 = sub * (NBLK / 4);
            int i1 = min(i0 + (NBLK / 4), nCnt);

            if (span <= MAXSPAN) {
                float acc = 0.0f, rc = 0.0f;
                int curb = -1;
                for (int i = i0; i < i1; ++i) {
                    const float* sp = &sb[i * 6];
                    float tv = 0.0f;
#pragma unroll
                    for (int k = 0; k < 6; ++k) tv = fmaf(sp[k], w1r[k], tv);
                    float a = fmaxf(fmaf(dvb[i], tv, b1f), 0.0f);
                    int bb = btb[i];
                    if (bb != curb) {
                        if (curb >= 0) {
                            atomicAdd(&gacc[(curb - bfirst) * HID + f], acc);
                            if (f == 0) atomicAdd(&gcnt[curb - bfirst], rc);
                        }
                        acc = 0.0f; rc = 0.0f; curb = bb;
                    }
                    acc += a; rc += 1.0f;
                }
                if (curb >= 0) {
                    atomicAdd(&gacc[(curb - bfirst) * HID + f], acc);
                    if (f == 0) atomicAdd(&gcnt[curb - bfirst], rc);
                }
                __syncthreads();
                for (int idx = t; idx < span * HID; idx += T) {
                    int r = idx >> 7, ff = idx & (HID - 1);
                    int gid = bfirst + r;
                    float v = gacc[r * HID + ff];
                    if (gid == bprev || gid == bnext) atomicAdd(&gsum[gid * HID + ff], v);
                    else gsum[gid * HID + ff] = v;
                }
                if (t < span) {
                    int gid = bfirst + t;
                    float v = gcnt[t];
                    if (gid == bprev || gid == bnext) atomicAdd(&cnt[gid], v);
                    else cnt[gid] = v;
                }
            } else {
                float acc = 0.0f, rc = 0.0f;
                int curb = -1;
                for (int i = i0; i < i1; ++i) {
                    const float* sp = &sb[i * 6];
                    float tv = 0.0f;
#pragma unroll
                    for (int k = 0; k < 6; ++k) tv = fmaf(sp[k], w1r[k], tv);
                    float a = fmaxf(fmaf(dvb[i], tv, b1f), 0.0f);
                    int bb = btb[i];
                    if (bb != curb) {
                        if (curb >= 0) {
                            atomicAdd(&gsum[curb * HID + f], acc);
                            if (f == 0) atomicAdd(&cnt[curb], rc);
                        }
                        acc = 0.0f; rc = 0.0f; curb = bb;
                    }
                    acc += a; rc += 1.0f;
                }
                if (curb >= 0) {
                    atomicAdd(&gsum[curb * HID + f], acc);
                    if (f == 0) atomicAdd(&cnt[curb], rc);
                }
            }
        }
    }
    gridbar(bar, grp, baseRoot + 5, baseGrp + 5);

    // ---- S6: head MLP + log_softmax (128 blocks x 4 graphs) ----
    {
        if (b < N_GRAPH / 4) {
            float* sg  = (float*)smem;
            float* sg2 = sg + 4 * HID;
            int sub = t >> 7, tt = t & (HID - 1);
            int g = b * 4 + sub;

            float ic = 1.0f / fmaxf(cnt[g], 1.0f);
            sg[sub * HID + tt] = gsum[g * HID + tt] * ic;
            __syncthreads();

            float acc = bl[tt];
            for (int k = 0; k < HID; ++k) acc = fmaf(sg[sub * HID + k], wl[k * HID + tt], acc);
            sg2[sub * HID + tt] = fmaxf(acc, 0.0f);
            __syncthreads();

            if (tt < N_ACT) {
                float l = b2[tt];
                for (int f2 = 0; f2 < HID; ++f2) l = fmaf(sg2[sub * HID + f2], w2[f2 * N_ACT + tt], l);
                float m = l;
#pragma unroll
                for (int off = 32; off > 0; off >>= 1) m = fmaxf(m, __shfl_xor(m, off));
                float e = expf(l - m);
                float ssum = e;
#pragma unroll
                for (int off = 32; off > 0; off >>= 1) ssum += __shfl_xor(ssum, off);
                out[g * N_ACT + tt] = l - m - logf(ssum);
            }
        }
    }
}

// ===================== fallback path (round-1, known-correct) =====================

__global__ void k_init(float* __restrict__ deg, float* __restrict__ gsum,
                       float* __restrict__ cnt) {
    int i = blockIdx.x * blockDim.x + threadIdx.x;
    if (i < N_NODES) deg[i] = 1.0f;
    if (i < N_GRAPH * HID) gsum[i] = 0.0f;
    if (i < N_GRAPH) cnt[i] = 0.0f;
}

__global__ void k_deg(const int* __restrict__ ei, float* __restrict__ deg) {
    int e = blockIdx.x * blockDim.x + threadIdx.x;
    if (e < N_EDGES) atomicAdd(&deg[ei[N_EDGES + e]], 1.0f);
}

__global__ void k_scale(const float* __restrict__ x, const int* __restrict__ batch,
                        const float* __restrict__ deg, float* __restrict__ dinv,
                        float* __restrict__ xs, float* __restrict__ s,
                        float* __restrict__ cnt) {
    int n = blockIdx.x * blockDim.x + threadIdx.x;
    if (n >= N_NODES) return;
    float dv = rsqrtf(deg[n]);
    dinv[n] = dv;
#pragma unroll
    for (int k = 0; k < 6; ++k) {
        float v = x[n * 6 + k] * dv;
        xs[n * 6 + k] = v;
        s[n * 6 + k] = v;
    }
    atomicAdd(&cnt[batch[n]], 1.0f);
}

__global__ void k_scatter(const int* __restrict__ ei, const float* __restrict__ xs,
                          float* __restrict__ s) {
    int e = blockIdx.x * blockDim.x + threadIdx.x;
    if (e >= N_EDGES) return;
    int src = ei[e];
    int dst = ei[N_EDGES + e];
#pragma unroll
    for (int k = 0; k < 6; ++k)
        atomicAdd(&s[dst * 6 + k], xs[src * 6 + k]);
}

__global__ __launch_bounds__(256) void k_node(const float* __restrict__ s,
                                              const float* __restrict__ dinv,
                                              const int* __restrict__ batch,
                                              const float* __restrict__ w1,
                                              const float* __restrict__ b1,
                                              float* __restrict__ gsum) {
    int f = threadIdx.x & (HID - 1);
    int sub = threadIdx.x >> 7;
    int base = blockIdx.x * 16 + sub * 8;
    float w1r[6];
#pragma unroll
    for (int k = 0; k < 6; ++k) w1r[k] = w1[k * HID + f];
    float b1f = b1[f];
    float acc = 0.0f;
    int curb = -1;
    for (int i = 0; i < 8; ++i) {
        int n = base + i;
        if (n >= N_NODES) break;
        float t = 0.0f;
#pragma unroll
        for (int k = 0; k < 6; ++k) t = fmaf(s[n * 6 + k], w1r[k], t);
        float a = fmaxf(fmaf(dinv[n], t, b1f), 0.0f);
        int b = batch[n];
        if (b != curb) {
            if (curb >= 0) atomicAdd(&gsum[curb * HID + f], acc);
            acc = 0.0f;
            curb = b;
        }
        acc += a;
    }
    if (curb >= 0) atomicAdd(&gsum[curb * HID + f], acc);
}

__global__ __launch_bounds__(128) void k_head(const float* __restrict__ gsum,
                                              const float* __restrict__ cnt,
                                              const float* __restrict__ wl,
                                              const float* __restrict__ bl,
                                              const float* __restrict__ w2,
                                              const float* __restrict__ b2,
                                              float* __restrict__ out) {
    __shared__ float sg[HID];
    __shared__ float sg2[HID];
    int g = blockIdx.x;
    int t = threadIdx.x;

    float ic = 1.0f / fmaxf(cnt[g], 1.0f);
    sg[t] = gsum[g * HID + t] * ic;
    __syncthreads();

    float acc = bl[t];
    for (int k = 0; k < HID; ++k) acc = fmaf(sg[k], wl[k * HID + t], acc);
    sg2[t] = fmaxf(acc, 0.0f);
    __syncthreads();

    if (t < N_ACT) {
        float l = b2[t];
        for (int f = 0; f < HID; ++f) l = fmaf(sg2[f], w2[f * N_ACT + t], l);
        float m = l;
#pragma unroll
        for (int off = 32; off > 0; off >>= 1) m = fmaxf(m, __shfl_xor(m, off));
        float e = expf(l - m);
        float ssum = e;
#pragma unroll
        for (int off = 32; off > 0; off >>= 1) ssum += __shfl_xor(ssum, off);
        out[g * N_ACT + t] = l - m - logf(ssum);
    }
}

// ===================== launch =====================

extern "C" void kernel_launch(void* const* d_in, const int* in_sizes, int n_in,
                              void* d_out, int out_size, void* d_ws, size_t ws_size,
                              hipStream_t stream) {
    const float* x     = (const float*)d_in[0];
    const int*   ei    = (const int*)d_in[1];
    const int*   batch = (const int*)d_in[2];
    const float* w1    = (const float*)d_in[3];
    const float* b1    = (const float*)d_in[4];
    const float* wl    = (const float*)d_in[5];
    const float* bl    = (const float*)d_in[6];
    const float* w2    = (const float*)d_in[7];
    const float* b2    = (const float*)d_in[8];
    float* out = (float*)d_out;
    float* ws = (float*)d_ws;

    if (ws_size >= NEED_BYTES) {
        k_mega<<<G, T, 0, stream>>>(x, ei, batch, w1, b1, wl, bl, w2, b2, out, ws);
    } else {
        float* deg  = ws;
        float* dinv = deg + N_NODES;
        float* xs   = dinv + N_NODES;
        float* s    = xs + N6;
        float* gsum = s + N6;
        float* cnt  = gsum + N_GRAPH * HID;

        k_init<<<(N_GRAPH * HID + 255) / 256, 256, 0, stream>>>(deg, gsum, cnt);
        k_deg<<<(N_EDGES + 255) / 256, 256, 0, stream>>>(ei, deg);
        k_scale<<<(N_NODES + 255) / 256, 256, 0, stream>>>(x, batch, deg, dinv, xs, s, cnt);
        k_scatter<<<(N_EDGES + 255) / 256, 256, 0, stream>>>(ei, xs, s);
        k_node<<<(N_NODES + 15) / 16, 256, 0, stream>>>(s, dinv, batch, w1, b1, gsum);
        k_head<<<N_GRAPH, 128, 0, stream>>>(gsum, cnt, wl, bl, w2, b2, out);
    }
}

// Round 10
// 131.931 us; speedup vs baseline: 5.0673x; 5.0673x over previous
//
#include <hip/hip_runtime.h>
#include <math.h>

#define N_NODES 50000
#define N_EDGES 800000
#define HID     128
#define N_ACT   64
#define N_GRAPH 512
#define N6      (N_NODES * 6)

// bucketing
#define NWF   2048                 // nodes per dst-window
#define LOGW  11
#define WF    25
#define CAP   40960
#define CB    16                   // feat sub-chunks per window (4 iters @512t)
#define EPB   2048                 // edges per place-block @512t
#define PB    ((N_EDGES + EPB - 1) / EPB)   // 391

// node stage
#define NBLK    256
#define MAXSPAN 16

// ws layout (float-sized slots)
#define F_BUCKET 0                          // WF*CAP ints
#define F_CURSOR (F_BUCKET + WF * CAP)      // 32 ints (memset 128B)
#define F_GSUM   (F_CURSOR + 32)            // N_GRAPH*HID
#define F_CNT    (F_GSUM + N_GRAPH * HID)   // N_GRAPH
#define F_DINV   (F_CNT + N_GRAPH)          // N_NODES
#define F_XSPAD  (F_DINV + N_NODES)         // N_NODES*8
#define F_SPART  (F_XSPAD + N_NODES * 8)    // CB*N6
#define F_TOTAL  (F_SPART + CB * N6)
#define NEED_BYTES ((size_t)F_TOTAL * 4)
#define ZFLOATS (N_GRAPH * HID + N_GRAPH)   // gsum|cnt = 66048 (div 4)

// ===================== fast path =====================

// place edges into dst-window buckets; spare lanes zero gsum|cnt (consumed
// by k_node two dispatches later).
__global__ __launch_bounds__(512) void k_place(const int* __restrict__ ei,
                                               int* __restrict__ bucket,
                                               int* __restrict__ cursor,
                                               float* __restrict__ zbase) {
    __shared__ int lc[WF], lb[WF];
    int t = threadIdx.x;
    int tid = blockIdx.x * 512 + t;
    if (tid < ZFLOATS / 4) ((float4*)zbase)[tid] = make_float4(0, 0, 0, 0);

    if (t < WF) lc[t] = 0;
    __syncthreads();
    int e0 = blockIdx.x * EPB;
    int pk[4], wli[4];
#pragma unroll
    for (int i = 0; i < 4; ++i) {
        int e = e0 + i * 512 + t;
        wli[i] = -1;
        if (e < N_EDGES) {
            int src = ei[e], dst = ei[N_EDGES + e];
            int w = dst >> LOGW;
            int lp = atomicAdd(&lc[w], 1);
            pk[i] = ((dst - (w << LOGW)) << 16) | src;
            wli[i] = (w << 16) | lp;
        }
    }
    __syncthreads();
    if (t < WF) lb[t] = atomicAdd(&cursor[t], lc[t]);
    __syncthreads();
#pragma unroll
    for (int i = 0; i < 4; ++i) {
        if (wli[i] >= 0) {
            int w = wli[i] >> 16, lp = wli[i] & 0xffff;
            int pos = lb[w] + lp;
            if ((unsigned)pos < CAP) bucket[w * CAP + pos] = pk[i];
        }
    }
}

// fused degree+scale: one block per window. Scans the window bucket once
// (batched 4x), full-window LDS histogram, then dinv + xs_pad directly.
// No cross-block dependency, no degree-partial round-trip.
__global__ __launch_bounds__(512) void k_degscale(const int* __restrict__ bucket,
                                                  const int* __restrict__ cursor,
                                                  const float* __restrict__ x,
                                                  float* __restrict__ dinv,
                                                  float* __restrict__ xs_pad) {
    __shared__ float hist[NWF];
    int w = blockIdx.x, t = threadIdx.x;
    float4* h4 = (float4*)hist;
    if (t < NWF / 4) h4[t] = make_float4(0, 0, 0, 0);
    __syncthreads();
    int cw = min(cursor[w], CAP);
    const int* bp = bucket + w * CAP;
    int e = t;
    for (; e + 3 * 512 < cw; e += 4 * 512) {
        int p0 = bp[e], p1 = bp[e + 512], p2 = bp[e + 1024], p3 = bp[e + 1536];
        atomicAdd(&hist[((unsigned)p0) >> 16], 1.0f);
        atomicAdd(&hist[((unsigned)p1) >> 16], 1.0f);
        atomicAdd(&hist[((unsigned)p2) >> 16], 1.0f);
        atomicAdd(&hist[((unsigned)p3) >> 16], 1.0f);
    }
    for (; e < cw; e += 512) atomicAdd(&hist[((unsigned)bp[e]) >> 16], 1.0f);
    __syncthreads();
    int base = w * NWF;
#pragma unroll
    for (int j = 0; j < 2; ++j) {
        int i = 2 * (t + j * 512);               // even offset in window
        int n = base + i;
        if (n < N_NODES) {                        // N_NODES even -> n+1 valid
            float dv0 = rsqrtf(1.0f + hist[i]);
            float dv1 = rsqrtf(1.0f + hist[i + 1]);
            dinv[n] = dv0; dinv[n + 1] = dv1;
            const float4* xp = (const float4*)(x + (size_t)n * 6);
            float4 xa = xp[0], xb = xp[1], xc = xp[2];
            float4* op = (float4*)(xs_pad + (size_t)n * 8);
            op[0] = make_float4(xa.x * dv0, xa.y * dv0, xa.z * dv0, xa.w * dv0);
            op[1] = make_float4(xb.x * dv0, xb.y * dv0, 0.0f, 0.0f);
            op[2] = make_float4(xb.z * dv1, xb.w * dv1, xc.x * dv1, xc.y * dv1);
            op[3] = make_float4(xc.z * dv1, xc.w * dv1, 0.0f, 0.0f);
        }
    }
}

// feature scatter: block (w,c) scans 1/CB of window w's bucket (4 batched
// iters @512t, all gathers issued before atomics), LDS-accumulates, flushes.
__global__ __launch_bounds__(512) void k_feat(const int* __restrict__ bucket,
                                              const int* __restrict__ cursor,
                                              const float* __restrict__ xs_pad,
                                              float* __restrict__ s_part) {
    __shared__ float h[NWF * 6];
    int w = blockIdx.x, c = blockIdx.y;
    int t = threadIdx.x;
    float4* h4 = (float4*)h;
    for (int i = t; i < NWF * 6 / 4; i += 512) h4[i] = make_float4(0, 0, 0, 0);
    __syncthreads();
    int cw = min(cursor[w], CAP);
    const int* bp = bucket + w * CAP;
    const int stride = CB * 512;
    int e = c * 512 + t;
    for (; e + 3 * stride < cw; e += 4 * stride) {
        int p0 = bp[e], p1 = bp[e + stride], p2 = bp[e + 2 * stride], p3 = bp[e + 3 * stride];
        const float4* q0 = (const float4*)(xs_pad + (size_t)(p0 & 0xffff) * 8);
        const float4* q1 = (const float4*)(xs_pad + (size_t)(p1 & 0xffff) * 8);
        const float4* q2 = (const float4*)(xs_pad + (size_t)(p2 & 0xffff) * 8);
        const float4* q3 = (const float4*)(xs_pad + (size_t)(p3 & 0xffff) * 8);
        float4 a0 = q0[0], b0 = q0[1];
        float4 a1 = q1[0], b1 = q1[1];
        float4 a2 = q2[0], b2 = q2[1];
        float4 a3 = q3[0], b3 = q3[1];
        float* hp;
        hp = &h[(((unsigned)p0) >> 16) * 6];
        atomicAdd(hp + 0, a0.x); atomicAdd(hp + 1, a0.y); atomicAdd(hp + 2, a0.z);
        atomicAdd(hp + 3, a0.w); atomicAdd(hp + 4, b0.x); atomicAdd(hp + 5, b0.y);
        hp = &h[(((unsigned)p1) >> 16) * 6];
        atomicAdd(hp + 0, a1.x); atomicAdd(hp + 1, a1.y); atomicAdd(hp + 2, a1.z);
        atomicAdd(hp + 3, a1.w); atomicAdd(hp + 4, b1.x); atomicAdd(hp + 5, b1.y);
        hp = &h[(((unsigned)p2) >> 16) * 6];
        atomicAdd(hp + 0, a2.x); atomicAdd(hp + 1, a2.y); atomicAdd(hp + 2, a2.z);
        atomicAdd(hp + 3, a2.w); atomicAdd(hp + 4, b2.x); atomicAdd(hp + 5, b2.y);
        hp = &h[(((unsigned)p3) >> 16) * 6];
        atomicAdd(hp + 0, a3.x); atomicAdd(hp + 1, a3.y); atomicAdd(hp + 2, a3.z);
        atomicAdd(hp + 3, a3.w); atomicAdd(hp + 4, b3.x); atomicAdd(hp + 5, b3.y);
    }
    for (; e < cw; e += stride) {
        int p = bp[e];
        const float4* q = (const float4*)(xs_pad + (size_t)(p & 0xffff) * 8);
        float4 a = q[0], b = q[1];
        float* hp = &h[(((unsigned)p) >> 16) * 6];
        atomicAdd(hp + 0, a.x); atomicAdd(hp + 1, a.y); atomicAdd(hp + 2, a.z);
        atomicAdd(hp + 3, a.w); atomicAdd(hp + 4, b.x); atomicAdd(hp + 5, b.y);
    }
    __syncthreads();
    int gb = w * NWF * 6;
    int lim = min(NWF * 6, N6 - gb);      // multiple of 4
    float4* sp4 = (float4*)(s_part + (size_t)c * N6 + gb);
    for (int i = t; i < lim / 4; i += 512) sp4[i] = h4[i];
}

// block: NBLK nodes; partial-reduce into LDS, W1+ReLU, per-graph LDS rows,
// flush interior graphs with plain stores, boundary graphs with atomics.
__global__ __launch_bounds__(256) void k_node_f(const float* __restrict__ s_part,
                                                const float* __restrict__ xs_pad,
                                                const float* __restrict__ dinv,
                                                const int* __restrict__ batch,
                                                const float* __restrict__ w1,
                                                const float* __restrict__ b1,
                                                float* __restrict__ gsum,
                                                float* __restrict__ cnt) {
    __shared__ float sb[NBLK * 6];
    __shared__ float dvb[NBLK];
    __shared__ int   btb[NBLK];
    __shared__ float gacc[MAXSPAN][HID];
    __shared__ float gcnt[MAXSPAN];
    __shared__ int   sbnd[2];

    int nb0 = blockIdx.x * NBLK;
    int nEnd = min(nb0 + NBLK, N_NODES);
    int nCnt = nEnd - nb0;
    int lim = nCnt * 6;

    {
        float4* sb4 = (float4*)sb;
        int nv = lim >> 2;
        int g4base = (nb0 * 6) >> 2;
        for (int i = threadIdx.x; i < nv; i += 256) {
            float4 v = make_float4(0, 0, 0, 0);
#pragma unroll
            for (int c = 0; c < CB; ++c) {
                float4 p = ((const float4*)(s_part + (size_t)c * N6))[g4base + i];
                v.x += p.x; v.y += p.y; v.z += p.z; v.w += p.w;
            }
            sb4[i] = v;
        }
    }
    for (int i = threadIdx.x; i < nCnt; i += 256) {
        dvb[i] = dinv[nb0 + i];
        btb[i] = batch[nb0 + i];
    }
    if (threadIdx.x == 0) {
        sbnd[0] = (nb0 > 0) ? batch[nb0 - 1] : -1;
        sbnd[1] = (nEnd < N_NODES) ? batch[nEnd] : -1;
    }
    for (int i = threadIdx.x; i < MAXSPAN * HID; i += 256) ((float*)gacc)[i] = 0.0f;
    if (threadIdx.x < MAXSPAN) gcnt[threadIdx.x] = 0.0f;
    __syncthreads();

    for (int i = threadIdx.x; i < nCnt; i += 256) {
        const float4* xp = (const float4*)(xs_pad + (size_t)(nb0 + i) * 8);
        float4 a = xp[0], b = xp[1];
        float* sp = &sb[i * 6];
        sp[0] += a.x; sp[1] += a.y; sp[2] += a.z;
        sp[3] += a.w; sp[4] += b.x; sp[5] += b.y;
    }
    __syncthreads();

    int f = threadIdx.x & (HID - 1);
    int sub = threadIdx.x >> 7;
    float w1r[6];
#pragma unroll
    for (int k = 0; k < 6; ++k) w1r[k] = w1[k * HID + f];
    float b1f = b1[f];

    int bfirst = btb[0];
    int blast = btb[nCnt - 1];
    int span = blast - bfirst + 1;
    int bprev = sbnd[0], bnext = sbnd[1];
    int i0 = sub * (NBLK / 2);
    int i1 = min(i0 + (NBLK / 2), nCnt);

    if (span <= MAXSPAN) {
        float acc = 0.0f, rc = 0.0f;
        int curb = -1;
        for (int i = i0; i < i1; ++i) {
            const float* sp = &sb[i * 6];
            float t = 0.0f;
#pragma unroll
            for (int k = 0; k < 6; ++k) t = fmaf(sp[k], w1r[k], t);
            float a = fmaxf(fmaf(dvb[i], t, b1f), 0.0f);
            int b = btb[i];
            if (b != curb) {
                if (curb >= 0) {
                    atomicAdd(&gacc[curb - bfirst][f], acc);
                    if (f == 0) atomicAdd(&gcnt[curb - bfirst], rc);
                }
                acc = 0.0f; rc = 0.0f; curb = b;
            }
            acc += a; rc += 1.0f;
        }
        if (curb >= 0) {
            atomicAdd(&gacc[curb - bfirst][f], acc);
            if (f == 0) atomicAdd(&gcnt[curb - bfirst], rc);
        }
        __syncthreads();
        for (int idx = threadIdx.x; idx < span * HID; idx += 256) {
            int r = idx >> 7, ff = idx & (HID - 1);
            int gid = bfirst + r;
            float v = gacc[r][ff];
            if (gid == bprev || gid == bnext) atomicAdd(&gsum[gid * HID + ff], v);
            else gsum[gid * HID + ff] = v;
        }
        if (threadIdx.x < span) {
            int gid = bfirst + threadIdx.x;
            float v = gcnt[threadIdx.x];
            if (gid == bprev || gid == bnext) atomicAdd(&cnt[gid], v);
            else cnt[gid] = v;
        }
    } else {
        float acc = 0.0f, rc = 0.0f;
        int curb = -1;
        for (int i = i0; i < i1; ++i) {
            const float* sp = &sb[i * 6];
            float t = 0.0f;
#pragma unroll
            for (int k = 0; k < 6; ++k) t = fmaf(sp[k], w1r[k], t);
            float a = fmaxf(fmaf(dvb[i], t, b1f), 0.0f);
            int b = btb[i];
            if (b != curb) {
                if (curb >= 0) {
                    atomicAdd(&gsum[curb * HID + f], acc);
                    if (f == 0) atomicAdd(&cnt[curb], rc);
                }
                acc = 0.0f; rc = 0.0f; curb = b;
            }
            acc += a; rc += 1.0f;
        }
        if (curb >= 0) {
            atomicAdd(&gsum[curb * HID + f], acc);
            if (f == 0) atomicAdd(&cnt[curb], rc);
        }
    }
}

// head: 128 blocks x 4 graphs @512t (structure verified in rounds 8/9).
__global__ __launch_bounds__(512) void k_head4(const float* __restrict__ gsum,
                                               const float* __restrict__ cnt,
                                               const float* __restrict__ wl,
                                               const float* __restrict__ bl,
                                               const float* __restrict__ w2,
                                               const float* __restrict__ b2,
                                               float* __restrict__ out) {
    __shared__ float sg[4 * HID];
    __shared__ float sg2[4 * HID];
    int t = threadIdx.x;
    int sub = t >> 7, tt = t & (HID - 1);
    int g = blockIdx.x * 4 + sub;

    float ic = 1.0f / fmaxf(cnt[g], 1.0f);
    sg[sub * HID + tt] = gsum[g * HID + tt] * ic;
    __syncthreads();

    float acc = bl[tt];
    for (int k = 0; k < HID; ++k) acc = fmaf(sg[sub * HID + k], wl[k * HID + tt], acc);
    sg2[sub * HID + tt] = fmaxf(acc, 0.0f);
    __syncthreads();

    if (tt < N_ACT) {
        float l = b2[tt];
        for (int f = 0; f < HID; ++f) l = fmaf(sg2[sub * HID + f], w2[f * N_ACT + tt], l);
        float m = l;
#pragma unroll
        for (int off = 32; off > 0; off >>= 1) m = fmaxf(m, __shfl_xor(m, off));
        float e = expf(l - m);
        float ssum = e;
#pragma unroll
        for (int off = 32; off > 0; off >>= 1) ssum += __shfl_xor(ssum, off);
        out[g * N_ACT + tt] = l - m - logf(ssum);
    }
}

// ===================== fallback path (round-1, known-correct) =====================

__global__ void k_init(float* __restrict__ deg, float* __restrict__ gsum,
                       float* __restrict__ cnt) {
    int i = blockIdx.x * blockDim.x + threadIdx.x;
    if (i < N_NODES) deg[i] = 1.0f;
    if (i < N_GRAPH * HID) gsum[i] = 0.0f;
    if (i < N_GRAPH) cnt[i] = 0.0f;
}

__global__ void k_deg(const int* __restrict__ ei, float* __restrict__ deg) {
    int e = blockIdx.x * blockDim.x + threadIdx.x;
    if (e < N_EDGES) atomicAdd(&deg[ei[N_EDGES + e]], 1.0f);
}

__global__ void k_scale(const float* __restrict__ x, const int* __restrict__ batch,
                        const float* __restrict__ deg, float* __restrict__ dinv,
                        float* __restrict__ xs, float* __restrict__ s,
                        float* __restrict__ cnt) {
    int n = blockIdx.x * blockDim.x + threadIdx.x;
    if (n >= N_NODES) return;
    float dv = rsqrtf(deg[n]);
    dinv[n] = dv;
#pragma unroll
    for (int k = 0; k < 6; ++k) {
        float v = x[n * 6 + k] * dv;
        xs[n * 6 + k] = v;
        s[n * 6 + k] = v;
    }
    atomicAdd(&cnt[batch[n]], 1.0f);
}

__global__ void k_scatter(const int* __restrict__ ei, const float* __restrict__ xs,
                          float* __restrict__ s) {
    int e = blockIdx.x * blockDim.x + threadIdx.x;
    if (e >= N_EDGES) return;
    int src = ei[e];
    int dst = ei[N_EDGES + e];
#pragma unroll
    for (int k = 0; k < 6; ++k)
        atomicAdd(&s[dst * 6 + k], xs[src * 6 + k]);
}

__global__ __launch_bounds__(256) void k_node(const float* __restrict__ s,
                                              const float* __restrict__ dinv,
                                              const int* __restrict__ batch,
                                              const float* __restrict__ w1,
                                              const float* __restrict__ b1,
                                              float* __restrict__ gsum) {
    int f = threadIdx.x & (HID - 1);
    int sub = threadIdx.x >> 7;
    int base = blockIdx.x * 16 + sub * 8;
    float w1r[6];
#pragma unroll
    for (int k = 0; k < 6; ++k) w1r[k] = w1[k * HID + f];
    float b1f = b1[f];
    float acc = 0.0f;
    int curb = -1;
    for (int i = 0; i < 8; ++i) {
        int n = base + i;
        if (n >= N_NODES) break;
        float t = 0.0f;
#pragma unroll
        for (int k = 0; k < 6; ++k) t = fmaf(s[n * 6 + k], w1r[k], t);
        float a = fmaxf(fmaf(dinv[n], t, b1f), 0.0f);
        int b = batch[n];
        if (b != curb) {
            if (curb >= 0) atomicAdd(&gsum[curb * HID + f], acc);
            acc = 0.0f;
            curb = b;
        }
        acc += a;
    }
    if (curb >= 0) atomicAdd(&gsum[curb * HID + f], acc);
}

__global__ __launch_bounds__(128) void k_head(const float* __restrict__ gsum,
                                              const float* __restrict__ cnt,
                                              const float* __restrict__ wl,
                                              const float* __restrict__ bl,
                                              const float* __restrict__ w2,
                                              const float* __restrict__ b2,
                                              float* __restrict__ out) {
    __shared__ float sg[HID];
    __shared__ float sg2[HID];
    int g = blockIdx.x;
    int t = threadIdx.x;

    float ic = 1.0f / fmaxf(cnt[g], 1.0f);
    sg[t] = gsum[g * HID + t] * ic;
    __syncthreads();

    float acc = bl[t];
    for (int k = 0; k < HID; ++k) acc = fmaf(sg[k], wl[k * HID + t], acc);
    sg2[t] = fmaxf(acc, 0.0f);
    __syncthreads();

    if (t < N_ACT) {
        float l = b2[t];
        for (int f = 0; f < HID; ++f) l = fmaf(sg2[f], w2[f * N_ACT + t], l);
        float m = l;
#pragma unroll
        for (int off = 32; off > 0; off >>= 1) m = fmaxf(m, __shfl_xor(m, off));
        float e = expf(l - m);
        float ssum = e;
#pragma unroll
        for (int off = 32; off > 0; off >>= 1) ssum += __shfl_xor(ssum, off);
        out[g * N_ACT + t] = l - m - logf(ssum);
    }
}

// ===================== launch =====================

extern "C" void kernel_launch(void* const* d_in, const int* in_sizes, int n_in,
                              void* d_out, int out_size, void* d_ws, size_t ws_size,
                              hipStream_t stream) {
    const float* x     = (const float*)d_in[0];
    const int*   ei    = (const int*)d_in[1];
    const int*   batch = (const int*)d_in[2];
    const float* w1    = (const float*)d_in[3];
    const float* b1    = (const float*)d_in[4];
    const float* wl    = (const float*)d_in[5];
    const float* bl    = (const float*)d_in[6];
    const float* w2    = (const float*)d_in[7];
    const float* b2    = (const float*)d_in[8];
    float* out = (float*)d_out;
    float* ws = (float*)d_ws;

    if (ws_size >= NEED_BYTES) {
        int*   bucket = (int*)(ws + F_BUCKET);
        int*   cursor = (int*)(ws + F_CURSOR);
        float* gsum   = ws + F_GSUM;
        float* cnt    = ws + F_CNT;
        float* dinv   = ws + F_DINV;
        float* xs_pad = ws + F_XSPAD;
        float* s_part = ws + F_SPART;

        hipMemsetAsync(cursor, 0, 32 * sizeof(int), stream);
        k_place<<<PB, 512, 0, stream>>>(ei, bucket, cursor, gsum);
        k_degscale<<<WF, 512, 0, stream>>>(bucket, cursor, x, dinv, xs_pad);
        k_feat<<<dim3(WF, CB), 512, 0, stream>>>(bucket, cursor, xs_pad, s_part);
        k_node_f<<<(N_NODES + NBLK - 1) / NBLK, 256, 0, stream>>>(s_part, xs_pad, dinv, batch, w1, b1, gsum, cnt);
        k_head4<<<N_GRAPH / 4, 512, 0, stream>>>(gsum, cnt, wl, bl, w2, b2, out);
    } else {
        float* deg  = ws;
        float* dinv = deg + N_NODES;
        float* xs   = dinv + N_NODES;
        float* s    = xs + N6;
        float* gsum = s + N6;
        float* cnt  = gsum + N_GRAPH * HID;

        k_init<<<(N_GRAPH * HID + 255) / 256, 256, 0, stream>>>(deg, gsum, cnt);
        k_deg<<<(N_EDGES + 255) / 256, 256, 0, stream>>>(ei, deg);
        k_scale<<<(N_NODES + 255) / 256, 256, 0, stream>>>(x, batch, deg, dinv, xs, s, cnt);
        k_scatter<<<(N_EDGES + 255) / 256, 256, 0, stream>>>(ei, xs, s);
        k_node<<<(N_NODES + 15) / 16, 256, 0, stream>>>(s, dinv, batch, w1, b1, gsum);
        k_head<<<N_GRAPH, 128, 0, stream>>>(gsum, cnt, wl, bl, w2, b2, out);
    }
}

// Round 11
// 97.743 us; speedup vs baseline: 6.8397x; 1.3498x over previous
//
#include <hip/hip_runtime.h>
#include <math.h>

#define N_NODES 50000
#define N_EDGES 800000
#define HID     128
#define N_ACT   64
#define N_GRAPH 512
#define N6      (N_NODES * 6)

// bucketing
#define NWF   2048                 // nodes per dst-window
#define LOGW  11
#define WF    25
#define CAP   40960
#define CB    16                   // feat sub-chunks per window (4 batched iters @512t)
#define DC    16                   // deg sub-chunks per window
#define EPB   2048                 // edges per place-block @512t
#define PB    ((N_EDGES + EPB - 1) / EPB)   // 391

// node stage
#define NBLK    256
#define MAXSPAN 16

// ws layout (float-sized slots)
#define F_BUCKET 0                          // WF*CAP ints
#define F_CURSOR (F_BUCKET + WF * CAP)      // 32 ints (memset 128B)
#define F_GSUM   (F_CURSOR + 32)            // N_GRAPH*HID
#define F_CNT    (F_GSUM + N_GRAPH * HID)   // N_GRAPH
#define F_DINV   (F_CNT + N_GRAPH)          // N_NODES
#define F_XSPAD  (F_DINV + N_NODES)         // N_NODES*8
#define F_DEGP   (F_XSPAD + N_NODES * 8)    // DC*N_NODES
#define F_SPART  (F_DEGP + DC * N_NODES)    // CB*N6
#define F_TOTAL  (F_SPART + CB * N6)
#define NEED_BYTES ((size_t)F_TOTAL * 4)
#define ZFLOATS (N_GRAPH * HID + N_GRAPH)   // gsum|cnt = 66048 (div 4)

// ===================== fast path =====================

// place edges into dst-window buckets; spare lanes zero gsum|cnt (consumed
// by k_node_f three dispatches later). [proven round 10]
__global__ __launch_bounds__(512) void k_place(const int* __restrict__ ei,
                                               int* __restrict__ bucket,
                                               int* __restrict__ cursor,
                                               float* __restrict__ zbase) {
    __shared__ int lc[WF], lb[WF];
    int t = threadIdx.x;
    int tid = blockIdx.x * 512 + t;
    if (tid < ZFLOATS / 4) ((float4*)zbase)[tid] = make_float4(0, 0, 0, 0);

    if (t < WF) lc[t] = 0;
    __syncthreads();
    int e0 = blockIdx.x * EPB;
    int pk[4], wli[4];
#pragma unroll
    for (int i = 0; i < 4; ++i) {
        int e = e0 + i * 512 + t;
        wli[i] = -1;
        if (e < N_EDGES) {
            int src = ei[e], dst = ei[N_EDGES + e];
            int w = dst >> LOGW;
            int lp = atomicAdd(&lc[w], 1);
            pk[i] = ((dst - (w << LOGW)) << 16) | src;
            wli[i] = (w << 16) | lp;
        }
    }
    __syncthreads();
    if (t < WF) lb[t] = atomicAdd(&cursor[t], lc[t]);
    __syncthreads();
#pragma unroll
    for (int i = 0; i < 4; ++i) {
        if (wli[i] >= 0) {
            int w = wli[i] >> 16, lp = wli[i] & 0xffff;
            int pos = lb[w] + lp;
            if ((unsigned)pos < CAP) bucket[w * CAP + pos] = pk[i];
        }
    }
}

// degree partials: block (w,c) scans 1/DC of window w's bucket (batched 4x
// @512t), histograms the full 2048-node window in LDS, writes partial.
// [proven round 6 — 400 blocks, ~4 iters each]
__global__ __launch_bounds__(512) void k_degp(const int* __restrict__ bucket,
                                              const int* __restrict__ cursor,
                                              float* __restrict__ degp) {
    __shared__ float hist[NWF];
    int w = blockIdx.x, c = blockIdx.y;
    int t = threadIdx.x;
    for (int i = t; i < NWF; i += 512) hist[i] = 0.0f;
    __syncthreads();
    int cw = min(cursor[w], CAP);
    const int* bp = bucket + w * CAP;
    const int stride = DC * 512;
    int e = c * 512 + t;
    for (; e + 3 * stride < cw; e += 4 * stride) {
        int p0 = bp[e], p1 = bp[e + stride], p2 = bp[e + 2 * stride], p3 = bp[e + 3 * stride];
        atomicAdd(&hist[((unsigned)p0) >> 16], 1.0f);
        atomicAdd(&hist[((unsigned)p1) >> 16], 1.0f);
        atomicAdd(&hist[((unsigned)p2) >> 16], 1.0f);
        atomicAdd(&hist[((unsigned)p3) >> 16], 1.0f);
    }
    for (; e < cw; e += stride) atomicAdd(&hist[((unsigned)bp[e]) >> 16], 1.0f);
    __syncthreads();
    int nb = w * NWF;
    int lim = min(NWF, N_NODES - nb);
    for (int i = t; i < lim; i += 512) degp[c * N_NODES + nb + i] = hist[i];
}

// reduce DC degree partials -> dinv, xs_pad (2 nodes/thread, float4-aligned x)
// [proven round 6]
__global__ __launch_bounds__(256) void k_scale2(const float* __restrict__ degp,
                                                const float* __restrict__ x,
                                                float* __restrict__ dinv,
                                                float* __restrict__ xs_pad) {
    int n = blockIdx.x * 512 + 2 * threadIdx.x;
    if (n >= N_NODES) return;                 // N_NODES even -> n+1 also valid
    float d0 = 1.0f, d1 = 1.0f;               // self-loop
#pragma unroll
    for (int c = 0; c < DC; ++c) {
        d0 += degp[c * N_NODES + n];
        d1 += degp[c * N_NODES + n + 1];
    }
    float dv0 = rsqrtf(d0), dv1 = rsqrtf(d1);
    dinv[n] = dv0; dinv[n + 1] = dv1;
    const float4* xp = (const float4*)(x + (size_t)n * 6);
    float4 xa = xp[0], xb = xp[1], xc = xp[2];
    float4* op = (float4*)(xs_pad + (size_t)n * 8);
    op[0] = make_float4(xa.x * dv0, xa.y * dv0, xa.z * dv0, xa.w * dv0);
    op[1] = make_float4(xb.x * dv0, xb.y * dv0, 0.0f, 0.0f);
    op[2] = make_float4(xb.z * dv1, xb.w * dv1, xc.x * dv1, xc.y * dv1);
    op[3] = make_float4(xc.z * dv1, xc.w * dv1, 0.0f, 0.0f);
}

// feature scatter: block (w,c) scans 1/CB of window w's bucket (batched 4x
// @512t, all gathers issued before atomics), LDS-accumulates, flushes.
// [proven round 6]
__global__ __launch_bounds__(512) void k_feat(const int* __restrict__ bucket,
                                              const int* __restrict__ cursor,
                                              const float* __restrict__ xs_pad,
                                              float* __restrict__ s_part) {
    __shared__ float h[NWF * 6];
    int w = blockIdx.x, c = blockIdx.y;
    int t = threadIdx.x;
    float4* h4 = (float4*)h;
    for (int i = t; i < NWF * 6 / 4; i += 512) h4[i] = make_float4(0, 0, 0, 0);
    __syncthreads();
    int cw = min(cursor[w], CAP);
    const int* bp = bucket + w * CAP;
    const int stride = CB * 512;
    int e = c * 512 + t;
    for (; e + 3 * stride < cw; e += 4 * stride) {
        int p0 = bp[e], p1 = bp[e + stride], p2 = bp[e + 2 * stride], p3 = bp[e + 3 * stride];
        const float4* q0 = (const float4*)(xs_pad + (size_t)(p0 & 0xffff) * 8);
        const float4* q1 = (const float4*)(xs_pad + (size_t)(p1 & 0xffff) * 8);
        const float4* q2 = (const float4*)(xs_pad + (size_t)(p2 & 0xffff) * 8);
        const float4* q3 = (const float4*)(xs_pad + (size_t)(p3 & 0xffff) * 8);
        float4 a0 = q0[0], b0 = q0[1];
        float4 a1 = q1[0], b1 = q1[1];
        float4 a2 = q2[0], b2 = q2[1];
        float4 a3 = q3[0], b3 = q3[1];
        float* hp;
        hp = &h[(((unsigned)p0) >> 16) * 6];
        atomicAdd(hp + 0, a0.x); atomicAdd(hp + 1, a0.y); atomicAdd(hp + 2, a0.z);
        atomicAdd(hp + 3, a0.w); atomicAdd(hp + 4, b0.x); atomicAdd(hp + 5, b0.y);
        hp = &h[(((unsigned)p1) >> 16) * 6];
        atomicAdd(hp + 0, a1.x); atomicAdd(hp + 1, a1.y); atomicAdd(hp + 2, a1.z);
        atomicAdd(hp + 3, a1.w); atomicAdd(hp + 4, b1.x); atomicAdd(hp + 5, b1.y);
        hp = &h[(((unsigned)p2) >> 16) * 6];
        atomicAdd(hp + 0, a2.x); atomicAdd(hp + 1, a2.y); atomicAdd(hp + 2, a2.z);
        atomicAdd(hp + 3, a2.w); atomicAdd(hp + 4, b2.x); atomicAdd(hp + 5, b2.y);
        hp = &h[(((unsigned)p3) >> 16) * 6];
        atomicAdd(hp + 0, a3.x); atomicAdd(hp + 1, a3.y); atomicAdd(hp + 2, a3.z);
        atomicAdd(hp + 3, a3.w); atomicAdd(hp + 4, b3.x); atomicAdd(hp + 5, b3.y);
    }
    for (; e < cw; e += stride) {
        int p = bp[e];
        const float4* q = (const float4*)(xs_pad + (size_t)(p & 0xffff) * 8);
        float4 a = q[0], b = q[1];
        float* hp = &h[(((unsigned)p) >> 16) * 6];
        atomicAdd(hp + 0, a.x); atomicAdd(hp + 1, a.y); atomicAdd(hp + 2, a.z);
        atomicAdd(hp + 3, a.w); atomicAdd(hp + 4, b.x); atomicAdd(hp + 5, b.y);
    }
    __syncthreads();
    int gb = w * NWF * 6;
    int lim = min(NWF * 6, N6 - gb);      // multiple of 4
    float4* sp4 = (float4*)(s_part + (size_t)c * N6 + gb);
    for (int i = t; i < lim / 4; i += 512) sp4[i] = h4[i];
}

// block: NBLK nodes; partial-reduce into LDS, W1+ReLU, per-graph LDS rows,
// flush interior graphs with plain stores, boundary graphs with atomics.
// [proven round 6]
__global__ __launch_bounds__(256) void k_node_f(const float* __restrict__ s_part,
                                                const float* __restrict__ xs_pad,
                                                const float* __restrict__ dinv,
                                                const int* __restrict__ batch,
                                                const float* __restrict__ w1,
                                                const float* __restrict__ b1,
                                                float* __restrict__ gsum,
                                                float* __restrict__ cnt) {
    __shared__ float sb[NBLK * 6];
    __shared__ float dvb[NBLK];
    __shared__ int   btb[NBLK];
    __shared__ float gacc[MAXSPAN][HID];
    __shared__ float gcnt[MAXSPAN];
    __shared__ int   sbnd[2];

    int nb0 = blockIdx.x * NBLK;
    int nEnd = min(nb0 + NBLK, N_NODES);
    int nCnt = nEnd - nb0;
    int lim = nCnt * 6;

    {
        float4* sb4 = (float4*)sb;
        int nv = lim >> 2;
        int g4base = (nb0 * 6) >> 2;
        for (int i = threadIdx.x; i < nv; i += 256) {
            float4 v = make_float4(0, 0, 0, 0);
#pragma unroll
            for (int c = 0; c < CB; ++c) {
                float4 p = ((const float4*)(s_part + (size_t)c * N6))[g4base + i];
                v.x += p.x; v.y += p.y; v.z += p.z; v.w += p.w;
            }
            sb4[i] = v;
        }
    }
    for (int i = threadIdx.x; i < nCnt; i += 256) {
        dvb[i] = dinv[nb0 + i];
        btb[i] = batch[nb0 + i];
    }
    if (threadIdx.x == 0) {
        sbnd[0] = (nb0 > 0) ? batch[nb0 - 1] : -1;
        sbnd[1] = (nEnd < N_NODES) ? batch[nEnd] : -1;
    }
    for (int i = threadIdx.x; i < MAXSPAN * HID; i += 256) ((float*)gacc)[i] = 0.0f;
    if (threadIdx.x < MAXSPAN) gcnt[threadIdx.x] = 0.0f;
    __syncthreads();

    for (int i = threadIdx.x; i < nCnt; i += 256) {
        const float4* xp = (const float4*)(xs_pad + (size_t)(nb0 + i) * 8);
        float4 a = xp[0], b = xp[1];
        float* sp = &sb[i * 6];
        sp[0] += a.x; sp[1] += a.y; sp[2] += a.z;
        sp[3] += a.w; sp[4] += b.x; sp[5] += b.y;
    }
    __syncthreads();

    int f = threadIdx.x & (HID - 1);
    int sub = threadIdx.x >> 7;
    float w1r[6];
#pragma unroll
    for (int k = 0; k < 6; ++k) w1r[k] = w1[k * HID + f];
    float b1f = b1[f];

    int bfirst = btb[0];
    int blast = btb[nCnt - 1];
    int span = blast - bfirst + 1;
    int bprev = sbnd[0], bnext = sbnd[1];
    int i0 = sub * (NBLK / 2);
    int i1 = min(i0 + (NBLK / 2), nCnt);

    if (span <= MAXSPAN) {
        float acc = 0.0f, rc = 0.0f;
        int curb = -1;
        for (int i = i0; i < i1; ++i) {
            const float* sp = &sb[i * 6];
            float t = 0.0f;
#pragma unroll
            for (int k = 0; k < 6; ++k) t = fmaf(sp[k], w1r[k], t);
            float a = fmaxf(fmaf(dvb[i], t, b1f), 0.0f);
            int b = btb[i];
            if (b != curb) {
                if (curb >= 0) {
                    atomicAdd(&gacc[curb - bfirst][f], acc);
                    if (f == 0) atomicAdd(&gcnt[curb - bfirst], rc);
                }
                acc = 0.0f; rc = 0.0f; curb = b;
            }
            acc += a; rc += 1.0f;
        }
        if (curb >= 0) {
            atomicAdd(&gacc[curb - bfirst][f], acc);
            if (f == 0) atomicAdd(&gcnt[curb - bfirst], rc);
        }
        __syncthreads();
        for (int idx = threadIdx.x; idx < span * HID; idx += 256) {
            int r = idx >> 7, ff = idx & (HID - 1);
            int gid = bfirst + r;
            float v = gacc[r][ff];
            if (gid == bprev || gid == bnext) atomicAdd(&gsum[gid * HID + ff], v);
            else gsum[gid * HID + ff] = v;
        }
        if (threadIdx.x < span) {
            int gid = bfirst + threadIdx.x;
            float v = gcnt[threadIdx.x];
            if (gid == bprev || gid == bnext) atomicAdd(&cnt[gid], v);
            else cnt[gid] = v;
        }
    } else {
        float acc = 0.0f, rc = 0.0f;
        int curb = -1;
        for (int i = i0; i < i1; ++i) {
            const float* sp = &sb[i * 6];
            float t = 0.0f;
#pragma unroll
            for (int k = 0; k < 6; ++k) t = fmaf(sp[k], w1r[k], t);
            float a = fmaxf(fmaf(dvb[i], t, b1f), 0.0f);
            int b = btb[i];
            if (b != curb) {
                if (curb >= 0) {
                    atomicAdd(&gsum[curb * HID + f], acc);
                    if (f == 0) atomicAdd(&cnt[curb], rc);
                }
                acc = 0.0f; rc = 0.0f; curb = b;
            }
            acc += a; rc += 1.0f;
        }
        if (curb >= 0) {
            atomicAdd(&gsum[curb * HID + f], acc);
            if (f == 0) atomicAdd(&cnt[curb], rc);
        }
    }
}

// head: 128 blocks x 4 graphs @512t [proven rounds 8-10]
__global__ __launch_bounds__(512) void k_head4(const float* __restrict__ gsum,
                                               const float* __restrict__ cnt,
                                               const float* __restrict__ wl,
                                               const float* __restrict__ bl,
                                               const float* __restrict__ w2,
                                               const float* __restrict__ b2,
                                               float* __restrict__ out) {
    __shared__ float sg[4 * HID];
    __shared__ float sg2[4 * HID];
    int t = threadIdx.x;
    int sub = t >> 7, tt = t & (HID - 1);
    int g = blockIdx.x * 4 + sub;

    float ic = 1.0f / fmaxf(cnt[g], 1.0f);
    sg[sub * HID + tt] = gsum[g * HID + tt] * ic;
    __syncthreads();

    float acc = bl[tt];
    for (int k = 0; k < HID; ++k) acc = fmaf(sg[sub * HID + k], wl[k * HID + tt], acc);
    sg2[sub * HID + tt] = fmaxf(acc, 0.0f);
    __syncthreads();

    if (tt < N_ACT) {
        float l = b2[tt];
        for (int f = 0; f < HID; ++f) l = fmaf(sg2[sub * HID + f], w2[f * N_ACT + tt], l);
        float m = l;
#pragma unroll
        for (int off = 32; off > 0; off >>= 1) m = fmaxf(m, __shfl_xor(m, off));
        float e = expf(l - m);
        float ssum = e;
#pragma unroll
        for (int off = 32; off > 0; off >>= 1) ssum += __shfl_xor(ssum, off);
        out[g * N_ACT + tt] = l - m - logf(ssum);
    }
}

// ===================== fallback path (round-1, known-correct) =====================

__global__ void k_init(float* __restrict__ deg, float* __restrict__ gsum,
                       float* __restrict__ cnt) {
    int i = blockIdx.x * blockDim.x + threadIdx.x;
    if (i < N_NODES) deg[i] = 1.0f;
    if (i < N_GRAPH * HID) gsum[i] = 0.0f;
    if (i < N_GRAPH) cnt[i] = 0.0f;
}

__global__ void k_deg(const int* __restrict__ ei, float* __restrict__ deg) {
    int e = blockIdx.x * blockDim.x + threadIdx.x;
    if (e < N_EDGES) atomicAdd(&deg[ei[N_EDGES + e]], 1.0f);
}

__global__ void k_scale(const float* __restrict__ x, const int* __restrict__ batch,
                        const float* __restrict__ deg, float* __restrict__ dinv,
                        float* __restrict__ xs, float* __restrict__ s,
                        float* __restrict__ cnt) {
    int n = blockIdx.x * blockDim.x + threadIdx.x;
    if (n >= N_NODES) return;
    float dv = rsqrtf(deg[n]);
    dinv[n] = dv;
#pragma unroll
    for (int k = 0; k < 6; ++k) {
        float v = x[n * 6 + k] * dv;
        xs[n * 6 + k] = v;
        s[n * 6 + k] = v;
    }
    atomicAdd(&cnt[batch[n]], 1.0f);
}

__global__ void k_scatter(const int* __restrict__ ei, const float* __restrict__ xs,
                          float* __restrict__ s) {
    int e = blockIdx.x * blockDim.x + threadIdx.x;
    if (e >= N_EDGES) return;
    int src = ei[e];
    int dst = ei[N_EDGES + e];
#pragma unroll
    for (int k = 0; k < 6; ++k)
        atomicAdd(&s[dst * 6 + k], xs[src * 6 + k]);
}

__global__ __launch_bounds__(256) void k_node(const float* __restrict__ s,
                                              const float* __restrict__ dinv,
                                              const int* __restrict__ batch,
                                              const float* __restrict__ w1,
                                              const float* __restrict__ b1,
                                              float* __restrict__ gsum) {
    int f = threadIdx.x & (HID - 1);
    int sub = threadIdx.x >> 7;
    int base = blockIdx.x * 16 + sub * 8;
    float w1r[6];
#pragma unroll
    for (int k = 0; k < 6; ++k) w1r[k] = w1[k * HID + f];
    float b1f = b1[f];
    float acc = 0.0f;
    int curb = -1;
    for (int i = 0; i < 8; ++i) {
        int n = base + i;
        if (n >= N_NODES) break;
        float t = 0.0f;
#pragma unroll
        for (int k = 0; k < 6; ++k) t = fmaf(s[n * 6 + k], w1r[k], t);
        float a = fmaxf(fmaf(dinv[n], t, b1f), 0.0f);
        int b = batch[n];
        if (b != curb) {
            if (curb >= 0) atomicAdd(&gsum[curb * HID + f], acc);
            acc = 0.0f;
            curb = b;
        }
        acc += a;
    }
    if (curb >= 0) atomicAdd(&gsum[curb * HID + f], acc);
}

__global__ __launch_bounds__(128) void k_head(const float* __restrict__ gsum,
                                              const float* __restrict__ cnt,
                                              const float* __restrict__ wl,
                                              const float* __restrict__ bl,
                                              const float* __restrict__ w2,
                                              const float* __restrict__ b2,
                                              float* __restrict__ out) {
    __shared__ float sg[HID];
    __shared__ float sg2[HID];
    int g = blockIdx.x;
    int t = threadIdx.x;

    float ic = 1.0f / fmaxf(cnt[g], 1.0f);
    sg[t] = gsum[g * HID + t] * ic;
    __syncthreads();

    float acc = bl[t];
    for (int k = 0; k < HID; ++k) acc = fmaf(sg[k], wl[k * HID + t], acc);
    sg2[t] = fmaxf(acc, 0.0f);
    __syncthreads();

    if (t < N_ACT) {
        float l = b2[t];
        for (int f = 0; f < HID; ++f) l = fmaf(sg2[f], w2[f * N_ACT + t], l);
        float m = l;
#pragma unroll
        for (int off = 32; off > 0; off >>= 1) m = fmaxf(m, __shfl_xor(m, off));
        float e = expf(l - m);
        float ssum = e;
#pragma unroll
        for (int off = 32; off > 0; off >>= 1) ssum += __shfl_xor(ssum, off);
        out[g * N_ACT + t] = l - m - logf(ssum);
    }
}

// ===================== launch =====================

extern "C" void kernel_launch(void* const* d_in, const int* in_sizes, int n_in,
                              void* d_out, int out_size, void* d_ws, size_t ws_size,
                              hipStream_t stream) {
    const float* x     = (const float*)d_in[0];
    const int*   ei    = (const int*)d_in[1];
    const int*   batch = (const int*)d_in[2];
    const float* w1    = (const float*)d_in[3];
    const float* b1    = (const float*)d_in[4];
    const float* wl    = (const float*)d_in[5];
    const float* bl    = (const float*)d_in[6];
    const float* w2    = (const float*)d_in[7];
    const float* b2    = (const float*)d_in[8];
    float* out = (float*)d_out;
    float* ws = (float*)d_ws;

    if (ws_size >= NEED_BYTES) {
        int*   bucket = (int*)(ws + F_BUCKET);
        int*   cursor = (int*)(ws + F_CURSOR);
        float* gsum   = ws + F_GSUM;
        float* cnt    = ws + F_CNT;
        float* dinv   = ws + F_DINV;
        float* xs_pad = ws + F_XSPAD;
        float* degp   = ws + F_DEGP;
        float* s_part = ws + F_SPART;

        hipMemsetAsync(cursor, 0, 32 * sizeof(int), stream);
        k_place<<<PB, 512, 0, stream>>>(ei, bucket, cursor, gsum);
        k_degp<<<dim3(WF, DC), 512, 0, stream>>>(bucket, cursor, degp);
        k_scale2<<<(N_NODES + 511) / 512, 256, 0, stream>>>(degp, x, dinv, xs_pad);
        k_feat<<<dim3(WF, CB), 512, 0, stream>>>(bucket, cursor, xs_pad, s_part);
        k_node_f<<<(N_NODES + NBLK - 1) / NBLK, 256, 0, stream>>>(s_part, xs_pad, dinv, batch, w1, b1, gsum, cnt);
        k_head4<<<N_GRAPH / 4, 512, 0, stream>>>(gsum, cnt, wl, bl, w2, b2, out);
    } else {
        float* deg  = ws;
        float* dinv = deg + N_NODES;
        float* xs   = dinv + N_NODES;
        float* s    = xs + N6;
        float* gsum = s + N6;
        float* cnt  = gsum + N_GRAPH * HID;

        k_init<<<(N_GRAPH * HID + 255) / 256, 256, 0, stream>>>(deg, gsum, cnt);
        k_deg<<<(N_EDGES + 255) / 256, 256, 0, stream>>>(ei, deg);
        k_scale<<<(N_NODES + 255) / 256, 256, 0, stream>>>(x, batch, deg, dinv, xs, s, cnt);
        k_scatter<<<(N_EDGES + 255) / 256, 256, 0, stream>>>(ei, xs, s);
        k_node<<<(N_NODES + 15) / 16, 256, 0, stream>>>(s, dinv, batch, w1, b1, gsum);
        k_head<<<N_GRAPH, 128, 0, stream>>>(gsum, cnt, wl, bl, w2, b2, out);
    }
}